// Round 1
// baseline (343.718 us; speedup 1.0000x reference)
//
#include <hip/hip_runtime.h>

// ---------- constants for this problem ----------
#define BATCH 2
#define NTOK 2048          // image tokens per batch
#define MTOK 256           // text tokens per batch
#define CDIM 1024
#define NHEAD 16
#define HD 64
#define SEQ (NTOK + MTOK)  // 2304
#define TOK_X (BATCH * NTOK)   // 4096
#define TOK_Y (BATCH * MTOK)   // 512
#define BHN (BATCH * NHEAD)    // 32

typedef __attribute__((ext_vector_type(8))) short bf16x8;
typedef __attribute__((ext_vector_type(4))) float f32x4;

__device__ __forceinline__ float b2f(ushort u) {
    unsigned v = ((unsigned)u) << 16;
    return __builtin_bit_cast(float, v);
}
__device__ __forceinline__ ushort f2b(float f) {
    unsigned u = __builtin_bit_cast(unsigned, f);
    u += 0x7fffu + ((u >> 16) & 1u);   // round-to-nearest-even
    return (ushort)(u >> 16);
}

// ---------- cast fp32 -> bf16, 8 elems/thread ----------
__global__ __launch_bounds__(256) void cast_bf16(const float* __restrict__ in,
                                                 ushort* __restrict__ out, int n) {
    int i = (blockIdx.x * 256 + threadIdx.x) * 8;
    if (i >= n) return;
    float4 a = *(const float4*)(in + i);
    float4 b = *(const float4*)(in + i + 4);
    ushort tmp[8] = {f2b(a.x), f2b(a.y), f2b(a.z), f2b(a.w),
                     f2b(b.x), f2b(b.y), f2b(b.z), f2b(b.w)};
    *(uint4*)(out + i) = *(const uint4*)tmp;
}

// ---------- GEMM: C[M][N] = A[M][K] * Bt[N][K]^T + bias, bf16 in / (bf16|f32) out ----------
// 128x128 tile, BK=64, 256 threads = 2x2 waves of 64x64.
__device__ __forceinline__ void store_out(float* p, float v) { *p = v; }
__device__ __forceinline__ void store_out(ushort* p, float v) { *p = f2b(v); }

template <typename OutT>
__global__ __launch_bounds__(256) void gemm_bt_bias(const ushort* __restrict__ A,
                                                    const ushort* __restrict__ Bt,
                                                    const float* __restrict__ bias,
                                                    OutT* __restrict__ C,
                                                    int M, int N, int K) {
    __shared__ ushort As[128][72];   // +8 pad
    __shared__ ushort Bs[128][72];
    int tid = threadIdx.x;
    int lane = tid & 63;
    int w = tid >> 6;
    int wm = (w >> 1) * 64;
    int wn = (w & 1) * 64;
    int l15 = lane & 15;
    int quad = lane >> 4;
    int bm = blockIdx.y * 128;
    int bn = blockIdx.x * 128;

    f32x4 acc[4][4];
#pragma unroll
    for (int i = 0; i < 4; i++)
#pragma unroll
        for (int j = 0; j < 4; j++) acc[i][j] = (f32x4)0.0f;

    int sr = tid >> 3;          // 0..31
    int sc = (tid & 7) * 8;     // 0..56

    for (int k0 = 0; k0 < K; k0 += 64) {
        __syncthreads();
#pragma unroll
        for (int p = 0; p < 4; p++) {
            int r = sr + p * 32;
            *(uint4*)&As[r][sc] = *(const uint4*)&A[(size_t)(bm + r) * K + k0 + sc];
            *(uint4*)&Bs[r][sc] = *(const uint4*)&Bt[(size_t)(bn + r) * K + k0 + sc];
        }
        __syncthreads();
#pragma unroll
        for (int kk = 0; kk < 64; kk += 32) {
            bf16x8 af[4], bfr[4];
#pragma unroll
            for (int i = 0; i < 4; i++)
                af[i] = *(const bf16x8*)&As[wm + i * 16 + l15][kk + quad * 8];
#pragma unroll
            for (int j = 0; j < 4; j++)
                bfr[j] = *(const bf16x8*)&Bs[wn + j * 16 + l15][kk + quad * 8];
#pragma unroll
            for (int i = 0; i < 4; i++)
#pragma unroll
                for (int j = 0; j < 4; j++)
                    acc[i][j] = __builtin_amdgcn_mfma_f32_16x16x32_bf16(af[i], bfr[j], acc[i][j], 0, 0, 0);
        }
    }
#pragma unroll
    for (int i = 0; i < 4; i++) {
        int row0 = bm + wm + i * 16 + quad * 4;
#pragma unroll
        for (int j = 0; j < 4; j++) {
            int col = bn + wn + j * 16 + l15;
            float bv = bias[col];
#pragma unroll
            for (int r = 0; r < 4; r++) {
                store_out(&C[(size_t)(row0 + r) * N + col], acc[i][j][r] + bv);
            }
        }
    }
}

// ---------- reorg qkv: rmsnorm(q,k) + scatter to head-major, fold 1/sqrt(hd) into q ----------
// qkv: [TOK_X][3072] bf16  ->  qh [BHN][NTOK][64], kc/vc [BHN][SEQ][64] (first NTOK slots)
__global__ __launch_bounds__(256) void reorg_qkv(const ushort* __restrict__ qkv,
                                                 const float* __restrict__ qn_w,
                                                 const float* __restrict__ kn_w,
                                                 ushort* __restrict__ qh,
                                                 ushort* __restrict__ kc,
                                                 ushort* __restrict__ vc) {
    int wid = blockIdx.x * 4 + (threadIdx.x >> 6);
    int lane = threadIdx.x & 63;
    int h = wid & (NHEAD - 1);
    int t = wid >> 4;                 // token 0..4095
    int b = t >> 11;
    int n = t & (NTOK - 1);
    const ushort* row = qkv + (size_t)t * 3072;
    ushort qraw = row[h * 64 + lane];
    ushort kraw = row[1024 + h * 64 + lane];
    ushort vraw = row[2048 + h * 64 + lane];
    float qv = b2f(qraw), kv = b2f(kraw);
    float sq = qv * qv, sk = kv * kv;
#pragma unroll
    for (int m = 1; m < 64; m <<= 1) {
        sq += __shfl_xor(sq, m);
        sk += __shfl_xor(sk, m);
    }
    float rq = rsqrtf(sq * (1.0f / 64.0f) + 1e-6f);
    float rk = rsqrtf(sk * (1.0f / 64.0f) + 1e-6f);
    float qo = qv * rq * qn_w[lane] * 0.125f;   // scale = hd^-0.5 = 1/8
    float ko = kv * rk * kn_w[lane];
    size_t bh = (size_t)(b * NHEAD + h);
    qh[(bh * NTOK + n) * 64 + lane] = f2b(qo);
    kc[(bh * SEQ + n) * 64 + lane] = f2b(ko);
    vc[(bh * SEQ + n) * 64 + lane] = vraw;
}

// ---------- reorg kv (text tokens): rmsnorm(k) + scatter at seq offset NTOK ----------
__global__ __launch_bounds__(256) void reorg_kv(const ushort* __restrict__ kvb,
                                                const float* __restrict__ kn_w,
                                                ushort* __restrict__ kc,
                                                ushort* __restrict__ vc) {
    int wid = blockIdx.x * 4 + (threadIdx.x >> 6);
    int lane = threadIdx.x & 63;
    int h = wid & (NHEAD - 1);
    int t = wid >> 4;                 // token 0..511
    int b = t >> 8;
    int m = t & (MTOK - 1);
    const ushort* row = kvb + (size_t)t * 2048;
    ushort kraw = row[h * 64 + lane];
    ushort vraw = row[1024 + h * 64 + lane];
    float kv = b2f(kraw);
    float sk = kv * kv;
#pragma unroll
    for (int ms = 1; ms < 64; ms <<= 1) sk += __shfl_xor(sk, ms);
    float rk = rsqrtf(sk * (1.0f / 64.0f) + 1e-6f);
    float ko = kv * rk * kn_w[lane];
    size_t bh = (size_t)(b * NHEAD + h);
    kc[(bh * SEQ + NTOK + m) * 64 + lane] = f2b(ko);
    vc[(bh * SEQ + NTOK + m) * 64 + lane] = vraw;
}

// ---------- transpose V: vc [BHN][SEQ][64] -> vt [BHN][64][SEQ] ----------
__global__ __launch_bounds__(256) void transpose_v(const ushort* __restrict__ vc,
                                                   ushort* __restrict__ vt) {
    __shared__ ushort t[64][72];
    int bh = blockIdx.y;
    int s0 = blockIdx.x * 64;
    int tid = threadIdx.x;
    int r = tid >> 3, c = (tid & 7) * 8;
    const ushort* src = vc + ((size_t)bh * SEQ + s0) * 64;
    *(uint4*)&t[r][c] = *(const uint4*)&src[(size_t)r * 64 + c];
    *(uint4*)&t[r + 32][c] = *(const uint4*)&src[(size_t)(r + 32) * 64 + c];
    __syncthreads();
    ushort* dst = vt + (size_t)bh * 64 * SEQ + s0;
#pragma unroll
    for (int p = 0; p < 2; p++) {
        int d = (tid >> 3) + p * 32;
        int s8 = (tid & 7) * 8;
        ushort tmp[8];
#pragma unroll
        for (int i = 0; i < 8; i++) tmp[i] = t[s8 + i][d];
        *(uint4*)&dst[(size_t)d * SEQ + s8] = *(const uint4*)tmp;
    }
}

// ---------- flash attention: per (bh, qtile of 64). 4 waves x 16 q-rows ----------
// qh [BHN][NTOK][64] (pre-scaled), kc [BHN][SEQ][64], vt [BHN][64][SEQ]
// out: token-major [TOK_X][1024] bf16  (c = h*64+d)
__global__ __launch_bounds__(256) void attn_fwd(const ushort* __restrict__ qh,
                                                const ushort* __restrict__ kc,
                                                const ushort* __restrict__ vt,
                                                ushort* __restrict__ out) {
    __shared__ ushort Ks[64][72];      // [key][d]
    __shared__ ushort Vs[64][72];      // [d][key]
    __shared__ ushort Ps[4][16][80];   // per-wave P tile [q][key]
    int tid = threadIdx.x;
    int lane = tid & 63;
    int w = tid >> 6;
    int l15 = lane & 15;
    int quad = lane >> 4;
    int bh = blockIdx.y;
    int q0 = blockIdx.x * 64 + w * 16;   // this wave's q rows within the bh

    // Q A-fragments straight from global (row = l15, k = quad*8 within 32-chunk)
    const ushort* qptr = qh + ((size_t)bh * NTOK + q0 + l15) * 64 + quad * 8;
    bf16x8 qf[2];
    qf[0] = *(const bf16x8*)qptr;
    qf[1] = *(const bf16x8*)(qptr + 32);

    float m_i[4], l_i[4];
    f32x4 O[4];
#pragma unroll
    for (int r = 0; r < 4; r++) { m_i[r] = -1e30f; l_i[r] = 0.0f; }
#pragma unroll
    for (int j = 0; j < 4; j++) O[j] = (f32x4)0.0f;

    const ushort* kbase = kc + (size_t)bh * SEQ * 64;
    const ushort* vbase = vt + (size_t)bh * 64 * SEQ;
    int sr = tid >> 3, sc = (tid & 7) * 8;

    for (int s0 = 0; s0 < SEQ; s0 += 64) {
        __syncthreads();
        *(uint4*)&Ks[sr][sc] = *(const uint4*)&kbase[(size_t)(s0 + sr) * 64 + sc];
        *(uint4*)&Ks[sr + 32][sc] = *(const uint4*)&kbase[(size_t)(s0 + sr + 32) * 64 + sc];
        *(uint4*)&Vs[sr][sc] = *(const uint4*)&vbase[(size_t)sr * SEQ + s0 + sc];
        *(uint4*)&Vs[sr + 32][sc] = *(const uint4*)&vbase[(size_t)(sr + 32) * SEQ + s0 + sc];
        __syncthreads();

        // logits S = Q K^T  (already scaled via q)
        f32x4 S[4];
#pragma unroll
        for (int j = 0; j < 4; j++) S[j] = (f32x4)0.0f;
#pragma unroll
        for (int kk = 0; kk < 2; kk++) {
#pragma unroll
            for (int j = 0; j < 4; j++) {
                bf16x8 bfr = *(const bf16x8*)&Ks[j * 16 + l15][kk * 32 + quad * 8];
                S[j] = __builtin_amdgcn_mfma_f32_16x16x32_bf16(qf[kk], bfr, S[j], 0, 0, 0);
            }
        }
        // online softmax per owned row (row = quad*4 + r)
        float p[4][4];
#pragma unroll
        for (int r = 0; r < 4; r++) {
            float rm = fmaxf(fmaxf(S[0][r], S[1][r]), fmaxf(S[2][r], S[3][r]));
#pragma unroll
            for (int msk = 1; msk < 16; msk <<= 1) rm = fmaxf(rm, __shfl_xor(rm, msk));
            float mn = fmaxf(m_i[r], rm);
            float alpha = __expf(m_i[r] - mn);
            m_i[r] = mn;
            float rs = 0.0f;
#pragma unroll
            for (int j = 0; j < 4; j++) {
                float e = __expf(S[j][r] - mn);
                p[j][r] = e;
                rs += e;
            }
#pragma unroll
            for (int msk = 1; msk < 16; msk <<= 1) rs += __shfl_xor(rs, msk);
            l_i[r] = l_i[r] * alpha + rs;
#pragma unroll
            for (int j = 0; j < 4; j++) O[j][r] *= alpha;
        }
        // P -> wave-private LDS (C-layout -> A-layout round trip)
#pragma unroll
        for (int j = 0; j < 4; j++)
#pragma unroll
            for (int r = 0; r < 4; r++)
                Ps[w][quad * 4 + r][j * 16 + l15] = f2b(p[j][r]);
        // O += P V   (wave-private P, no barrier needed; compiler inserts lgkm waits)
#pragma unroll
        for (int kk = 0; kk < 2; kk++) {
            bf16x8 af = *(const bf16x8*)&Ps[w][l15][kk * 32 + quad * 8];
#pragma unroll
            for (int j = 0; j < 4; j++) {
                bf16x8 bfr = *(const bf16x8*)&Vs[j * 16 + l15][kk * 32 + quad * 8];
                O[j] = __builtin_amdgcn_mfma_f32_16x16x32_bf16(af, bfr, O[j], 0, 0, 0);
            }
        }
    }
    // epilogue: normalize and store token-major
    int b = bh >> 4, h = bh & 15;
#pragma unroll
    for (int r = 0; r < 4; r++) {
        float inv = 1.0f / l_i[r];
        int tok = (b << 11) + q0 + quad * 4 + r;
        size_t off = ((size_t)tok * NHEAD + h) * 64;
#pragma unroll
        for (int j = 0; j < 4; j++)
            out[off + j * 16 + l15] = f2b(O[j][r] * inv);
    }
}

// ---------- launch ----------
extern "C" void kernel_launch(void* const* d_in, const int* in_sizes, int n_in,
                              void* d_out, int out_size, void* d_ws, size_t ws_size,
                              hipStream_t stream) {
    const float* x      = (const float*)d_in[0];
    const float* y      = (const float*)d_in[1];
    const float* qkv_w  = (const float*)d_in[2];
    const float* qkv_b  = (const float*)d_in[3];
    const float* kv_w   = (const float*)d_in[4];
    const float* kv_b   = (const float*)d_in[5];
    const float* qn_w   = (const float*)d_in[6];
    const float* kn_w   = (const float*)d_in[7];
    const float* proj_w = (const float*)d_in[8];
    const float* proj_b = (const float*)d_in[9];
    float* outp = (float*)d_out;

    char* ws = (char*)d_ws;
    ushort* x_bf    = (ushort*)ws; ws += (size_t)TOK_X * CDIM * 2;         // 8 MB
    ushort* y_bf    = (ushort*)ws; ws += (size_t)TOK_Y * CDIM * 2;         // 1 MB
    ushort* qkvw_bf = (ushort*)ws; ws += (size_t)3 * CDIM * CDIM * 2;      // 6 MB
    ushort* kvw_bf  = (ushort*)ws; ws += (size_t)2 * CDIM * CDIM * 2;      // 4 MB
    ushort* projw_bf= (ushort*)ws; ws += (size_t)CDIM * CDIM * 2;          // 2 MB
    ushort* qkv     = (ushort*)ws; ws += (size_t)TOK_X * 3 * CDIM * 2;     // 24 MB
    ushort* kvb     = (ushort*)ws; ws += (size_t)TOK_Y * 2 * CDIM * 2;     // 2 MB
    ushort* qh      = (ushort*)ws; ws += (size_t)BHN * NTOK * 64 * 2;      // 8 MB
    ushort* kc      = (ushort*)ws; ws += (size_t)BHN * SEQ * 64 * 2;       // 9.2 MB
    ushort* vc      = (ushort*)ws; ws += (size_t)BHN * SEQ * 64 * 2;       // 9.2 MB
    ushort* vt      = (ushort*)ws; ws += (size_t)BHN * SEQ * 64 * 2;       // 9.2 MB
    ushort* ao      = (ushort*)ws; ws += (size_t)TOK_X * CDIM * 2;         // 8 MB

    // casts
    cast_bf16<<<TOK_X * CDIM / 8 / 256, 256, 0, stream>>>(x, x_bf, TOK_X * CDIM);
    cast_bf16<<<TOK_Y * CDIM / 8 / 256, 256, 0, stream>>>(y, y_bf, TOK_Y * CDIM);
    cast_bf16<<<3 * CDIM * CDIM / 8 / 256, 256, 0, stream>>>(qkv_w, qkvw_bf, 3 * CDIM * CDIM);
    cast_bf16<<<2 * CDIM * CDIM / 8 / 256, 256, 0, stream>>>(kv_w, kvw_bf, 2 * CDIM * CDIM);
    cast_bf16<<<CDIM * CDIM / 8 / 256, 256, 0, stream>>>(proj_w, projw_bf, CDIM * CDIM);

    // projections
    gemm_bt_bias<ushort><<<dim3(3 * CDIM / 128, TOK_X / 128), 256, 0, stream>>>(
        x_bf, qkvw_bf, qkv_b, qkv, TOK_X, 3 * CDIM, CDIM);
    gemm_bt_bias<ushort><<<dim3(2 * CDIM / 128, TOK_Y / 128), 256, 0, stream>>>(
        y_bf, kvw_bf, kv_b, kvb, TOK_Y, 2 * CDIM, CDIM);

    // rmsnorm + head-major reorg + concat
    reorg_qkv<<<TOK_X * NHEAD / 4, 256, 0, stream>>>(qkv, qn_w, kn_w, qh, kc, vc);
    reorg_kv<<<TOK_Y * NHEAD / 4, 256, 0, stream>>>(kvb, kn_w, kc, vc);
    transpose_v<<<dim3(SEQ / 64, BHN), 256, 0, stream>>>(vc, vt);

    // attention
    attn_fwd<<<dim3(NTOK / 64, BHN), 256, 0, stream>>>(qh, kc, vt, ao);

    // output projection (fp32 out)
    gemm_bt_bias<float><<<dim3(CDIM / 128, TOK_X / 128), 256, 0, stream>>>(
        ao, projw_bf, proj_b, outp, TOK_X, CDIM, CDIM);
}

// Round 4
// 304.496 us; speedup vs baseline: 1.1288x; 1.1288x over previous
//
#include <hip/hip_runtime.h>

// ---------- constants for this problem ----------
#define BATCH 2
#define NTOK 2048          // image tokens per batch
#define MTOK 256           // text tokens per batch
#define CDIM 1024
#define NHEAD 16
#define HD 64
#define SEQ (NTOK + MTOK)  // 2304
#define TOK_X (BATCH * NTOK)   // 4096
#define TOK_Y (BATCH * MTOK)   // 512
#define BHN (BATCH * NHEAD)    // 32

typedef __attribute__((ext_vector_type(8))) short bf16x8;
typedef __attribute__((ext_vector_type(4))) short bf16x4;
typedef __attribute__((ext_vector_type(4))) float f32x4;
typedef __attribute__((ext_vector_type(2))) unsigned int u32x2;

__device__ __forceinline__ float b2f(ushort u) {
    unsigned v = ((unsigned)u) << 16;
    return __builtin_bit_cast(float, v);
}
__device__ __forceinline__ ushort f2b(float f) {
    unsigned u = __builtin_bit_cast(unsigned, f);
    u += 0x7fffu + ((u >> 16) & 1u);   // round-to-nearest-even
    return (ushort)(u >> 16);
}
__device__ __forceinline__ unsigned pack2bf(float a, float b) {
    return ((unsigned)f2b(b) << 16) | (unsigned)f2b(a);
}

// ---------- cast fp32 -> bf16, 8 elems/thread ----------
__global__ __launch_bounds__(256) void cast_bf16(const float* __restrict__ in,
                                                 ushort* __restrict__ out, int n) {
    int i = (blockIdx.x * 256 + threadIdx.x) * 8;
    if (i >= n) return;
    float4 a = *(const float4*)(in + i);
    float4 b = *(const float4*)(in + i + 4);
    ushort tmp[8] = {f2b(a.x), f2b(a.y), f2b(a.z), f2b(a.w),
                     f2b(b.x), f2b(b.y), f2b(b.z), f2b(b.w)};
    *(uint4*)(out + i) = *(const uint4*)tmp;
}

// ---------- GEMM: C[M][N] = A[M][K] * Bt[N][K]^T + bias (R1 proven version) ----------
// 128x128 tile, BK=64, 256 threads = 2x2 waves of 64x64.
__device__ __forceinline__ void store_out(float* p, float v) { *p = v; }
__device__ __forceinline__ void store_out(ushort* p, float v) { *p = f2b(v); }

template <typename OutT>
__global__ __launch_bounds__(256) void gemm_bt_bias(const ushort* __restrict__ A,
                                                    const ushort* __restrict__ Bt,
                                                    const float* __restrict__ bias,
                                                    OutT* __restrict__ C,
                                                    int M, int N, int K) {
    __shared__ ushort As[128][72];   // +8 pad
    __shared__ ushort Bs[128][72];
    int tid = threadIdx.x;
    int lane = tid & 63;
    int w = tid >> 6;
    int wm = (w >> 1) * 64;
    int wn = (w & 1) * 64;
    int l15 = lane & 15;
    int quad = lane >> 4;
    int bm = blockIdx.y * 128;
    int bn = blockIdx.x * 128;

    f32x4 acc[4][4];
#pragma unroll
    for (int i = 0; i < 4; i++)
#pragma unroll
        for (int j = 0; j < 4; j++) acc[i][j] = (f32x4)0.0f;

    int sr = tid >> 3;          // 0..31
    int sc = (tid & 7) * 8;     // 0..56

    for (int k0 = 0; k0 < K; k0 += 64) {
        __syncthreads();
#pragma unroll
        for (int p = 0; p < 4; p++) {
            int r = sr + p * 32;
            *(uint4*)&As[r][sc] = *(const uint4*)&A[(size_t)(bm + r) * K + k0 + sc];
            *(uint4*)&Bs[r][sc] = *(const uint4*)&Bt[(size_t)(bn + r) * K + k0 + sc];
        }
        __syncthreads();
#pragma unroll
        for (int kk = 0; kk < 64; kk += 32) {
            bf16x8 af[4], bfr[4];
#pragma unroll
            for (int i = 0; i < 4; i++)
                af[i] = *(const bf16x8*)&As[wm + i * 16 + l15][kk + quad * 8];
#pragma unroll
            for (int j = 0; j < 4; j++)
                bfr[j] = *(const bf16x8*)&Bs[wn + j * 16 + l15][kk + quad * 8];
#pragma unroll
            for (int i = 0; i < 4; i++)
#pragma unroll
                for (int j = 0; j < 4; j++)
                    acc[i][j] = __builtin_amdgcn_mfma_f32_16x16x32_bf16(af[i], bfr[j], acc[i][j], 0, 0, 0);
        }
    }
#pragma unroll
    for (int i = 0; i < 4; i++) {
        int row0 = bm + wm + i * 16 + quad * 4;
#pragma unroll
        for (int j = 0; j < 4; j++) {
            int col = bn + wn + j * 16 + l15;
            float bv = bias[col];
#pragma unroll
            for (int r = 0; r < 4; r++) {
                store_out(&C[(size_t)(row0 + r) * N + col], acc[i][j][r] + bv);
            }
        }
    }
}

// ---------- reorg qkv: rmsnorm(q,k) + head-major scatter; q pre-scaled by log2e/8 ----------
__global__ __launch_bounds__(256) void reorg_qkv(const ushort* __restrict__ qkv,
                                                 const float* __restrict__ qn_w,
                                                 const float* __restrict__ kn_w,
                                                 ushort* __restrict__ qh,
                                                 ushort* __restrict__ kc,
                                                 ushort* __restrict__ vc) {
    int wid = blockIdx.x * 4 + (threadIdx.x >> 6);
    int lane = threadIdx.x & 63;
    int h = wid & (NHEAD - 1);
    int t = wid >> 4;                 // token 0..4095
    int b = t >> 11;
    int n = t & (NTOK - 1);
    const ushort* row = qkv + (size_t)t * 3072;
    ushort qraw = row[h * 64 + lane];
    ushort kraw = row[1024 + h * 64 + lane];
    ushort vraw = row[2048 + h * 64 + lane];
    float qv = b2f(qraw), kv = b2f(kraw);
    float sq = qv * qv, sk = kv * kv;
#pragma unroll
    for (int m = 1; m < 64; m <<= 1) {
        sq += __shfl_xor(sq, m);
        sk += __shfl_xor(sk, m);
    }
    float rq = rsqrtf(sq * (1.0f / 64.0f) + 1e-6f);
    float rk = rsqrtf(sk * (1.0f / 64.0f) + 1e-6f);
    // fold attention scale (1/8) AND log2(e) into q so softmax uses native v_exp_f32
    float qo = qv * rq * qn_w[lane] * (0.125f * 1.44269504088896f);
    float ko = kv * rk * kn_w[lane];
    size_t bh = (size_t)(b * NHEAD + h);
    qh[(bh * NTOK + n) * 64 + lane] = f2b(qo);
    kc[(bh * SEQ + n) * 64 + lane] = f2b(ko);
    vc[(bh * SEQ + n) * 64 + lane] = vraw;
}

// ---------- reorg kv (text tokens) ----------
__global__ __launch_bounds__(256) void reorg_kv(const ushort* __restrict__ kvb,
                                                const float* __restrict__ kn_w,
                                                ushort* __restrict__ kc,
                                                ushort* __restrict__ vc) {
    int wid = blockIdx.x * 4 + (threadIdx.x >> 6);
    int lane = threadIdx.x & 63;
    int h = wid & (NHEAD - 1);
    int t = wid >> 4;                 // token 0..511
    int b = t >> 8;
    int m = t & (MTOK - 1);
    const ushort* row = kvb + (size_t)t * 2048;
    ushort kraw = row[h * 64 + lane];
    ushort vraw = row[1024 + h * 64 + lane];
    float kv = b2f(kraw);
    float sk = kv * kv;
#pragma unroll
    for (int ms = 1; ms < 64; ms <<= 1) sk += __shfl_xor(sk, ms);
    float rk = rsqrtf(sk * (1.0f / 64.0f) + 1e-6f);
    float ko = kv * rk * kn_w[lane];
    size_t bh = (size_t)(b * NHEAD + h);
    kc[(bh * SEQ + NTOK + m) * 64 + lane] = f2b(ko);
    vc[(bh * SEQ + NTOK + m) * 64 + lane] = vraw;
}

// ---------- transpose V: vc [BHN][SEQ][64] -> vt [BHN][64][SEQ] ----------
__global__ __launch_bounds__(256) void transpose_v(const ushort* __restrict__ vc,
                                                   ushort* __restrict__ vt) {
    __shared__ ushort t[64][72];
    int bh = blockIdx.y;
    int s0 = blockIdx.x * 64;
    int tid = threadIdx.x;
    int r = tid >> 3, c = (tid & 7) * 8;
    const ushort* src = vc + ((size_t)bh * SEQ + s0) * 64;
    *(uint4*)&t[r][c] = *(const uint4*)&src[(size_t)r * 64 + c];
    *(uint4*)&t[r + 32][c] = *(const uint4*)&src[(size_t)(r + 32) * 64 + c];
    __syncthreads();
    ushort* dst = vt + (size_t)bh * 64 * SEQ + s0;
#pragma unroll
    for (int p = 0; p < 2; p++) {
        int d = (tid >> 3) + p * 32;
        int s8 = (tid & 7) * 8;
        ushort tmp[8];
#pragma unroll
        for (int i = 0; i < 8; i++) tmp[i] = t[s8 + i][d];
        *(uint4*)&dst[(size_t)d * SEQ + s8] = *(const uint4*)tmp;
    }
}

// ---------- flash attention, transposed-S formulation ----------
// S^T = K Q^T via mfma(A=Kfrag, B=Qfrag): C-layout gives lane (quad,l15):
//   ST[j][r] = S[q=l15][key = j*16 + quad*4 + r]  -- one query per lane.
// That register layout IS the B-operand layout of mfma_f32_16x16x16bf16_1k
// (k = quad*4+i, n = l15), so P^T feeds O^T = V^T P^T in-register: no LDS
// round-trip, no transposed-P bank conflicts. q pre-scaled by log2e/8.
__global__ __launch_bounds__(256) void attn_fwd(const ushort* __restrict__ qh,
                                                const ushort* __restrict__ kc,
                                                const ushort* __restrict__ vt,
                                                ushort* __restrict__ out) {
    __shared__ ushort Ks[64][72];      // [key][d]
    __shared__ ushort Vs[64][72];      // [d][key]
    int tid = threadIdx.x;
    int lane = tid & 63;
    int w = tid >> 6;
    int l15 = lane & 15;
    int quad = lane >> 4;
    int bh = blockIdx.y;
    int q0 = blockIdx.x * 64 + w * 16;   // this wave's q rows

    const ushort* qptr = qh + ((size_t)bh * NTOK + q0 + l15) * 64 + quad * 8;
    bf16x8 qf0 = *(const bf16x8*)qptr;
    bf16x8 qf1 = *(const bf16x8*)(qptr + 32);

    float m_i = -1e30f, l_i = 0.0f;
    f32x4 OT[4];                       // OT[jd][r] = O[q=l15][d=jd*16+quad*4+r]
#pragma unroll
    for (int jd = 0; jd < 4; jd++) OT[jd] = (f32x4)0.0f;

    const ushort* kbase = kc + (size_t)bh * SEQ * 64;
    const ushort* vbase = vt + (size_t)bh * 64 * SEQ;
    int sr = tid >> 3, sc = (tid & 7) * 8;

    for (int s0 = 0; s0 < SEQ; s0 += 64) {
        __syncthreads();
        *(uint4*)&Ks[sr][sc] = *(const uint4*)&kbase[(size_t)(s0 + sr) * 64 + sc];
        *(uint4*)&Ks[sr + 32][sc] = *(const uint4*)&kbase[(size_t)(s0 + sr + 32) * 64 + sc];
        *(uint4*)&Vs[sr][sc] = *(const uint4*)&vbase[(size_t)sr * SEQ + s0 + sc];
        *(uint4*)&Vs[sr + 32][sc] = *(const uint4*)&vbase[(size_t)(sr + 32) * SEQ + s0 + sc];
        __syncthreads();

        // S^T tiles: ST[j][r] = S[q=l15][key=j*16+quad*4+r] (log2 domain)
        f32x4 ST[4];
#pragma unroll
        for (int j = 0; j < 4; j++) ST[j] = (f32x4)0.0f;
#pragma unroll
        for (int j = 0; j < 4; j++) {
            bf16x8 kf = *(const bf16x8*)&Ks[j * 16 + l15][quad * 8];
            ST[j] = __builtin_amdgcn_mfma_f32_16x16x32_bf16(kf, qf0, ST[j], 0, 0, 0);
        }
#pragma unroll
        for (int j = 0; j < 4; j++) {
            bf16x8 kf = *(const bf16x8*)&Ks[j * 16 + l15][32 + quad * 8];
            ST[j] = __builtin_amdgcn_mfma_f32_16x16x32_bf16(kf, qf1, ST[j], 0, 0, 0);
        }

        // online softmax: all 64 keys for query l15 live in the 4 lanes {quad'*16+l15}
        float rm = ST[0][0];
#pragma unroll
        for (int j = 0; j < 4; j++)
#pragma unroll
            for (int r = 0; r < 4; r++) rm = fmaxf(rm, ST[j][r]);
        rm = fmaxf(rm, __shfl_xor(rm, 16));
        rm = fmaxf(rm, __shfl_xor(rm, 32));
        float mn = fmaxf(m_i, rm);
        float alpha = exp2f(m_i - mn);
        m_i = mn;
        float rs = 0.0f;
#pragma unroll
        for (int j = 0; j < 4; j++)
#pragma unroll
            for (int r = 0; r < 4; r++) {
                float e = exp2f(ST[j][r] - mn);
                ST[j][r] = e;
                rs += e;
            }
        rs += __shfl_xor(rs, 16);
        rs += __shfl_xor(rs, 32);
        l_i = l_i * alpha + rs;
#pragma unroll
        for (int jd = 0; jd < 4; jd++) OT[jd] *= alpha;

        // O^T += V^T P^T : A = V^T from Vs (4 contig bf16), B = P^T in-register
#pragma unroll
        for (int j = 0; j < 4; j++) {
            u32x2 packed;
            packed.x = pack2bf(ST[j][0], ST[j][1]);
            packed.y = pack2bf(ST[j][2], ST[j][3]);
            bf16x4 pb = __builtin_bit_cast(bf16x4, packed);
#pragma unroll
            for (int jd = 0; jd < 4; jd++) {
                bf16x4 vf = *(const bf16x4*)&Vs[jd * 16 + l15][j * 16 + quad * 4];
                OT[jd] = __builtin_amdgcn_mfma_f32_16x16x16bf16_1k(vf, pb, OT[jd], 0, 0, 0);
            }
        }
    }
    // epilogue: normalize, pack 4 bf16, 8B stores (token-major out)
    float inv = 1.0f / l_i;
    int b = bh >> 4, h = bh & 15;
    int tok = (b << 11) + q0 + l15;
    ushort* obase = out + ((size_t)tok * NHEAD + h) * 64;
#pragma unroll
    for (int jd = 0; jd < 4; jd++) {
        u32x2 pk;
        pk.x = pack2bf(OT[jd][0] * inv, OT[jd][1] * inv);
        pk.y = pack2bf(OT[jd][2] * inv, OT[jd][3] * inv);
        *(u32x2*)&obase[jd * 16 + quad * 4] = pk;
    }
}

// ---------- launch ----------
extern "C" void kernel_launch(void* const* d_in, const int* in_sizes, int n_in,
                              void* d_out, int out_size, void* d_ws, size_t ws_size,
                              hipStream_t stream) {
    const float* x      = (const float*)d_in[0];
    const float* y      = (const float*)d_in[1];
    const float* qkv_w  = (const float*)d_in[2];
    const float* qkv_b  = (const float*)d_in[3];
    const float* kv_w   = (const float*)d_in[4];
    const float* kv_b   = (const float*)d_in[5];
    const float* qn_w   = (const float*)d_in[6];
    const float* kn_w   = (const float*)d_in[7];
    const float* proj_w = (const float*)d_in[8];
    const float* proj_b = (const float*)d_in[9];
    float* outp = (float*)d_out;

    char* ws = (char*)d_ws;
    ushort* x_bf    = (ushort*)ws; ws += (size_t)TOK_X * CDIM * 2;
    ushort* y_bf    = (ushort*)ws; ws += (size_t)TOK_Y * CDIM * 2;
    ushort* qkvw_bf = (ushort*)ws; ws += (size_t)3 * CDIM * CDIM * 2;
    ushort* kvw_bf  = (ushort*)ws; ws += (size_t)2 * CDIM * CDIM * 2;
    ushort* projw_bf= (ushort*)ws; ws += (size_t)CDIM * CDIM * 2;
    ushort* qkv     = (ushort*)ws; ws += (size_t)TOK_X * 3 * CDIM * 2;
    ushort* kvb     = (ushort*)ws; ws += (size_t)TOK_Y * 2 * CDIM * 2;
    ushort* qh      = (ushort*)ws; ws += (size_t)BHN * NTOK * 64 * 2;
    ushort* kc      = (ushort*)ws; ws += (size_t)BHN * SEQ * 64 * 2;
    ushort* vc      = (ushort*)ws; ws += (size_t)BHN * SEQ * 64 * 2;
    ushort* vt      = (ushort*)ws; ws += (size_t)BHN * SEQ * 64 * 2;
    ushort* ao      = (ushort*)ws; ws += (size_t)TOK_X * CDIM * 2;

    cast_bf16<<<TOK_X * CDIM / 8 / 256, 256, 0, stream>>>(x, x_bf, TOK_X * CDIM);
    cast_bf16<<<TOK_Y * CDIM / 8 / 256, 256, 0, stream>>>(y, y_bf, TOK_Y * CDIM);
    cast_bf16<<<3 * CDIM * CDIM / 8 / 256, 256, 0, stream>>>(qkv_w, qkvw_bf, 3 * CDIM * CDIM);
    cast_bf16<<<2 * CDIM * CDIM / 8 / 256, 256, 0, stream>>>(kv_w, kvw_bf, 2 * CDIM * CDIM);
    cast_bf16<<<CDIM * CDIM / 8 / 256, 256, 0, stream>>>(proj_w, projw_bf, CDIM * CDIM);

    gemm_bt_bias<ushort><<<dim3(3 * CDIM / 128, TOK_X / 128), 256, 0, stream>>>(
        x_bf, qkvw_bf, qkv_b, qkv, TOK_X, 3 * CDIM, CDIM);
    gemm_bt_bias<ushort><<<dim3(2 * CDIM / 128, TOK_Y / 128), 256, 0, stream>>>(
        y_bf, kvw_bf, kv_b, kvb, TOK_Y, 2 * CDIM, CDIM);

    reorg_qkv<<<TOK_X * NHEAD / 4, 256, 0, stream>>>(qkv, qn_w, kn_w, qh, kc, vc);
    reorg_kv<<<TOK_Y * NHEAD / 4, 256, 0, stream>>>(kvb, kn_w, kc, vc);
    transpose_v<<<dim3(SEQ / 64, BHN), 256, 0, stream>>>(vc, vt);

    attn_fwd<<<dim3(NTOK / 64, BHN), 256, 0, stream>>>(qh, kc, vt, ao);

    gemm_bt_bias<float><<<dim3(CDIM / 128, TOK_X / 128), 256, 0, stream>>>(
        ao, projw_bf, proj_b, outp, TOK_X, CDIM, CDIM);
}